// Round 2
// baseline (2247.415 us; speedup 1.0000x reference)
//
#include <hip/hip_runtime.h>
#include <hip/hip_bf16.h>

#define NC 8192
#define NF 16384
#define NE 262144
#define TROW 8000   // 125 * 64

// ---------------- KNN (k=3) ----------------
__global__ __launch_bounds__(64) void knn_kernel(
    const float* __restrict__ pos, const int* __restrict__ batch,
    const float* __restrict__ pos_skip, const int* __restrict__ batch_skip,
    int* __restrict__ idx3, float* __restrict__ w3)
{
    const int t = blockIdx.x * 64 + threadIdx.x;
    const float py0 = pos_skip[t*3+0], py1 = pos_skip[t*3+1], py2 = pos_skip[t*3+2];
    const int by = batch_skip[t];
    float b0 = INFINITY, b1 = INFINITY, b2 = INFINITY;
    int i0 = 0, i1 = 0, i2 = 0;
    __shared__ float sx[1024*3];
    __shared__ int   sb[1024];
    for (int tile = 0; tile < NC; tile += 1024) {
        __syncthreads();
        for (int i = threadIdx.x; i < 1024*3; i += 64) sx[i] = pos[tile*3 + i];
        for (int i = threadIdx.x; i < 1024;   i += 64) sb[i] = batch[tile + i];
        __syncthreads();
        for (int j = 0; j < 1024; ++j) {
            float dx = py0 - sx[j*3+0];
            float dy = py1 - sx[j*3+1];
            float dz = py2 - sx[j*3+2];
            float d = dx*dx + dy*dy + dz*dz;
            if (sb[j] != by) d = INFINITY;
            if (d < b2) {
                int gj = tile + j;
                if (d < b1) {
                    b2 = b1; i2 = i1;
                    if (d < b0) { b1 = b0; i1 = i0; b0 = d; i0 = gj; }
                    else        { b1 = d;  i1 = gj; }
                } else { b2 = d; i2 = gj; }
            }
        }
    }
    idx3[t*3+0] = i0; idx3[t*3+1] = i1; idx3[t*3+2] = i2;
    w3[t*3+0] = 1.0f / fmaxf(b0, 1e-16f);
    w3[t*3+1] = 1.0f / fmaxf(b1, 1e-16f);
    w3[t*3+2] = 1.0f / fmaxf(b2, 1e-16f);
}

// ---------------- interpolate + concat -> X0 [NF,128] ----------------
__global__ __launch_bounds__(64) void interp_kernel(
    const float* __restrict__ x, const float* __restrict__ x_skip,
    const int* __restrict__ idx3, const float* __restrict__ w3,
    float* __restrict__ X0)
{
    const int n = blockIdx.x, c = threadIdx.x;
    const int j0 = idx3[n*3+0], j1 = idx3[n*3+1], j2 = idx3[n*3+2];
    const float w0 = w3[n*3+0], w1 = w3[n*3+1], w2 = w3[n*3+2];
    const float inv = 1.0f / (w0 + w1 + w2);
    float h = (w0 * x[j0*64+c] + w1 * x[j1*64+c] + w2 * x[j2*64+c]) * inv;
    X0[(size_t)n*128 + c]      = h;
    X0[(size_t)n*128 + 64 + c] = x_skip[n*64+c];
}

// ---------------- spline basis per edge + src/dst histograms ----------------
__global__ __launch_bounds__(256) void basis_kernel(
    const int* __restrict__ ei, const float* __restrict__ pos_skip,
    float* __restrict__ basis, uint2* __restrict__ wi8,
    int* __restrict__ cntD, int* __restrict__ cntS)
{
    const int e = blockIdx.x * 256 + threadIdx.x;
    const int src = ei[e], dst = ei[NE + e];
    float fr[3]; int lo[3];
    #pragma unroll
    for (int d = 0; d < 3; ++d) {
        float p = (pos_skip[dst*3+d] - pos_skip[src*3+d]) * 4.0f + 0.5f;
        p = fminf(fmaxf(p, 0.0f), 1.0f);
        float v = p * 4.0f;
        float l = fminf(floorf(v), 3.0f);
        fr[d] = v - l;
        lo[d] = (int)l;
    }
    unsigned int wlo = 0, whi = 0;
    #pragma unroll
    for (int s = 0; s < 8; ++s) {
        const int bit0 = s & 1, bit1 = (s >> 1) & 1, bit2 = (s >> 2) & 1;
        float b = (bit0 ? fr[0] : 1.0f - fr[0])
                * (bit1 ? fr[1] : 1.0f - fr[1])
                * (bit2 ? fr[2] : 1.0f - fr[2]);
        int w = (lo[0] + bit0) + 5 * (lo[1] + bit1) + 25 * (lo[2] + bit2);
        basis[(size_t)e*8 + s] = b;
        if (s < 4) wlo |= ((unsigned)w) << (8*s);
        else       whi |= ((unsigned)w) << (8*(s-4));
    }
    wi8[e] = make_uint2(wlo, whi);
    atomicAdd(&cntD[dst], 1);
    atomicAdd(&cntS[src], 1);
}

// ---------------- single-block exclusive scan over NF counts (+sentinel) ----------------
__global__ __launch_bounds__(1024) void scan_kernel(
    const int* __restrict__ cnt, int* __restrict__ offs, int* __restrict__ cursor)
{
    __shared__ int s[1024];
    __shared__ int carry_s;
    const int tid = threadIdx.x;
    if (tid == 0) carry_s = 0;
    __syncthreads();
    for (int ch = 0; ch < NF/1024; ++ch) {
        const int i = ch*1024 + tid;
        const int v = cnt[i];
        s[tid] = v;
        __syncthreads();
        for (int off = 1; off < 1024; off <<= 1) {
            int t = (tid >= off) ? s[tid - off] : 0;
            __syncthreads();
            s[tid] += t;
            __syncthreads();
        }
        const int incl  = s[tid];
        const int total = s[1023];
        const int base  = carry_s;
        const int excl  = base + incl - v;
        offs[i] = excl; cursor[i] = excl;
        __syncthreads();
        if (tid == 0) carry_s = base + total;
        __syncthreads();
    }
    if (tid == 0) offs[NF] = carry_s;   // sentinel == NE
}

// ---------------- scatter: edge permutation sorted by key ----------------
__global__ __launch_bounds__(256) void scatter_kernel(
    const int* __restrict__ key, int* __restrict__ cursor, int* __restrict__ perm)
{
    const int e = blockIdx.x * 256 + threadIdx.x;
    const int k = key[e];
    const int p = atomicAdd(&cursor[k], 1);
    perm[p] = e;
}

// ---------------- T_chunk = X_chunk @ W_flat  (fp32 vector GEMM, bf16 out) ----------------
// X pre-offset to chunk base; T is chunk-local [CH, 8000].
template<int KIN>
__global__ __launch_bounds__(256) void gemmT_kernel(
    const float* __restrict__ X, const float* __restrict__ W,
    __hip_bfloat16* __restrict__ T)
{
    __shared__ float As[64][68];   // [k][m], padded for float4-aligned rows
    __shared__ float Bs[64][64];   // [k][o]
    const int m0 = blockIdx.x * 64;
    const int kern = blockIdx.y;
    const float* Wk = W + (size_t)kern * KIN * 64;
    const int tx = threadIdx.x & 15, ty = threadIdx.x >> 4;
    float acc[4][4] = {};
    for (int k0 = 0; k0 < KIN; k0 += 64) {
        for (int i = threadIdx.x; i < 64*64; i += 256) {
            int m = i >> 6, k = i & 63;
            As[k][m] = X[(size_t)(m0+m)*KIN + k0 + k];
        }
        for (int i = threadIdx.x; i < 64*64; i += 256) {
            Bs[i>>6][i&63] = Wk[(size_t)(k0 + (i>>6))*64 + (i&63)];
        }
        __syncthreads();
        #pragma unroll 8
        for (int k = 0; k < 64; ++k) {
            float4 a = *(const float4*)&As[k][ty*4];
            float4 b = *(const float4*)&Bs[k][tx*4];
            acc[0][0] = fmaf(a.x, b.x, acc[0][0]);
            acc[0][1] = fmaf(a.x, b.y, acc[0][1]);
            acc[0][2] = fmaf(a.x, b.z, acc[0][2]);
            acc[0][3] = fmaf(a.x, b.w, acc[0][3]);
            acc[1][0] = fmaf(a.y, b.x, acc[1][0]);
            acc[1][1] = fmaf(a.y, b.y, acc[1][1]);
            acc[1][2] = fmaf(a.y, b.z, acc[1][2]);
            acc[1][3] = fmaf(a.y, b.w, acc[1][3]);
            acc[2][0] = fmaf(a.z, b.x, acc[2][0]);
            acc[2][1] = fmaf(a.z, b.y, acc[2][1]);
            acc[2][2] = fmaf(a.z, b.z, acc[2][2]);
            acc[2][3] = fmaf(a.z, b.w, acc[2][3]);
            acc[3][0] = fmaf(a.w, b.x, acc[3][0]);
            acc[3][1] = fmaf(a.w, b.y, acc[3][1]);
            acc[3][2] = fmaf(a.w, b.z, acc[3][2]);
            acc[3][3] = fmaf(a.w, b.w, acc[3][3]);
        }
        __syncthreads();
    }
    #pragma unroll
    for (int mm = 0; mm < 4; ++mm) {
        size_t base = (size_t)(m0 + ty*4 + mm) * TROW + kern*64 + tx*4;
        #pragma unroll
        for (int nn = 0; nn < 4; ++nn)
            T[base + nn] = __float2bfloat16(acc[mm][nn]);
    }
}

// ---------------- per-edge message for edges with src in chunk ----------------
// grid-stride over permS[offsS[c0] .. offsS[c1]) — counts read on device.
__global__ __launch_bounds__(256) void msg_kernel(
    const __hip_bfloat16* __restrict__ Tc, int n0,
    const float* __restrict__ basis, const uint2* __restrict__ wi8,
    const int* __restrict__ permS, const int* __restrict__ offsS,
    int c0, int c1, const int* __restrict__ esrc,
    __hip_bfloat16* __restrict__ msg)
{
    const int eBeg = offsS[c0];
    const int eEnd = offsS[c1];
    const int lane = threadIdx.x & 63;
    const int sub  = threadIdx.x >> 6;   // 4 edges per block
    for (int p = eBeg + blockIdx.x*4 + sub; p < eEnd; p += gridDim.x*4) {
        const int e = permS[p];
        const int src = esrc[e];
        const uint2 w8 = wi8[e];
        const float* bs = basis + (size_t)e*8;
        const __hip_bfloat16* Trow = Tc + (size_t)(src - n0) * TROW;
        float acc = 0.0f;
        #pragma unroll
        for (int s = 0; s < 4; ++s) {
            const int wk = (w8.x >> (8*s)) & 255;
            acc += bs[s] * __bfloat162float(Trow[wk*64 + lane]);
        }
        #pragma unroll
        for (int s = 0; s < 4; ++s) {
            const int wk = (w8.y >> (8*s)) & 255;
            acc += bs[4+s] * __bfloat162float(Trow[wk*64 + lane]);
        }
        msg[(size_t)e*64 + lane] = __float2bfloat16(acc);
    }
}

// ---------------- per-dst segment mean + root + bias + ELU ----------------
template<int KIN>
__global__ __launch_bounds__(64) void agg_kernel(
    const __hip_bfloat16* __restrict__ msg, const int* __restrict__ permD,
    const int* __restrict__ offsD, const int* __restrict__ cntD,
    const float* __restrict__ X, const float* __restrict__ root,
    const float* __restrict__ bias, float* __restrict__ Xout)
{
    const int n = blockIdx.x, c = threadIdx.x;
    float acc = 0.0f;
    const int beg = offsD[n], num = cntD[n];
    for (int t = 0; t < num; ++t) {
        const int e = permD[beg + t];
        acc += __bfloat162float(msg[(size_t)e*64 + c]);
    }
    const float agg = acc / fmaxf((float)num, 1.0f);
    const float* xr = X + (size_t)n * KIN;
    float r = 0.0f;
    #pragma unroll 16
    for (int i = 0; i < KIN; ++i) r = fmaf(xr[i], root[i*64 + c], r);
    float o = agg + r + bias[c];
    o = (o > 0.0f) ? o : expm1f(o);
    Xout[(size_t)n*64 + c] = o;
}

// ---------------- tail: pos_skip + batch_skip passthrough ----------------
__global__ __launch_bounds__(256) void tail_kernel(
    const float* __restrict__ pos_skip, const int* __restrict__ batch_skip,
    float* __restrict__ out)
{
    const int i = blockIdx.x * 256 + threadIdx.x;
    if (i < NF*3) out[1048576 + i] = pos_skip[i];
    if (i < NF)   ((int*)out)[1048576 + NF*3 + i] = batch_skip[i];
}

extern "C" void kernel_launch(void* const* d_in, const int* in_sizes, int n_in,
                              void* d_out, int out_size, void* d_ws, size_t ws_size,
                              hipStream_t stream)
{
    const float* x          = (const float*)d_in[0];
    const float* pos        = (const float*)d_in[1];
    const int*   batch      = (const int*)d_in[2];
    const float* x_skip     = (const float*)d_in[3];
    const float* pos_skip   = (const float*)d_in[4];
    const int*   batch_skip = (const int*)d_in[5];
    const int*   ei         = (const int*)d_in[6];
    const float* W0    = (const float*)d_in[7];
    const float* root0 = (const float*)d_in[8];
    const float* b0    = (const float*)d_in[9];
    const float* W1    = (const float*)d_in[10];
    const float* root1 = (const float*)d_in[11];
    const float* b1    = (const float*)d_in[12];
    const float* W2    = (const float*)d_in[13];
    const float* root2 = (const float*)d_in[14];
    const float* b2    = (const float*)d_in[15];

    char* wp = (char*)d_ws;
    size_t used = 0;
    auto carve = [&](size_t bytes) {
        char* p = wp;
        size_t a = (bytes + 255) & ~(size_t)255;
        wp += a; used += a;
        return p;
    };
    // fixed buffers (~64 MB)
    float* X0    = (float*)carve((size_t)NF * 128 * 4);
    float* X1    = (float*)carve((size_t)NF * 64 * 4);
    float* X2    = (float*)carve((size_t)NF * 64 * 4);
    float* basis = (float*)carve((size_t)NE * 8 * 4);
    uint2* wi8   = (uint2*)carve((size_t)NE * 8);
    __hip_bfloat16* msg = (__hip_bfloat16*)carve((size_t)NE * 64 * 2);
    int*   idx3  = (int*)carve((size_t)NF * 3 * 4);
    float* w3    = (float*)carve((size_t)NF * 3 * 4);
    int*   cntD    = (int*)carve((size_t)NF * 4);
    int*   offsD   = (int*)carve((size_t)(NF+1) * 4);
    int*   cursorD = (int*)carve((size_t)NF * 4);
    int*   permD   = (int*)carve((size_t)NE * 4);
    int*   cntS    = (int*)carve((size_t)NF * 4);
    int*   offsS   = (int*)carve((size_t)(NF+1) * 4);
    int*   cursorS = (int*)carve((size_t)NF * 4);
    int*   permS   = (int*)carve((size_t)NE * 4);
    // T chunk gets whatever remains; adapt chunk size to ws_size
    size_t remain = (ws_size > used) ? (ws_size - used) : 0;
    int CH = NF;
    while (CH > 512 && (size_t)CH * TROW * 2 > remain) CH >>= 1;
    __hip_bfloat16* T = (__hip_bfloat16*)wp;
    const int NCH = NF / CH;

    hipMemsetAsync(cntD, 0, (size_t)NF * 4, stream);
    hipMemsetAsync(cntS, 0, (size_t)NF * 4, stream);
    knn_kernel<<<NF/64, 64, 0, stream>>>(pos, batch, pos_skip, batch_skip, idx3, w3);
    interp_kernel<<<NF, 64, 0, stream>>>(x, x_skip, idx3, w3, X0);
    basis_kernel<<<NE/256, 256, 0, stream>>>(ei, pos_skip, basis, wi8, cntD, cntS);
    scan_kernel<<<1, 1024, 0, stream>>>(cntD, offsD, cursorD);
    scan_kernel<<<1, 1024, 0, stream>>>(cntS, offsS, cursorS);
    scatter_kernel<<<NE/256, 256, 0, stream>>>(ei + NE, cursorD, permD);  // key = dst
    scatter_kernel<<<NE/256, 256, 0, stream>>>(ei,      cursorS, permS);  // key = src

    // layer 0: in=128
    for (int c = 0; c < NCH; ++c) {
        gemmT_kernel<128><<<dim3(CH/64, 125), 256, 0, stream>>>(X0 + (size_t)c*CH*128, W0, T);
        msg_kernel<<<2048, 256, 0, stream>>>(T, c*CH, basis, wi8, permS, offsS, c*CH, (c+1)*CH, ei, msg);
    }
    agg_kernel<128><<<NF, 64, 0, stream>>>(msg, permD, offsD, cntD, X0, root0, b0, X1);
    // layer 1: in=64
    for (int c = 0; c < NCH; ++c) {
        gemmT_kernel<64><<<dim3(CH/64, 125), 256, 0, stream>>>(X1 + (size_t)c*CH*64, W1, T);
        msg_kernel<<<2048, 256, 0, stream>>>(T, c*CH, basis, wi8, permS, offsS, c*CH, (c+1)*CH, ei, msg);
    }
    agg_kernel<64><<<NF, 64, 0, stream>>>(msg, permD, offsD, cntD, X1, root1, b1, X2);
    // layer 2: in=64, h -> d_out
    for (int c = 0; c < NCH; ++c) {
        gemmT_kernel<64><<<dim3(CH/64, 125), 256, 0, stream>>>(X2 + (size_t)c*CH*64, W2, T);
        msg_kernel<<<2048, 256, 0, stream>>>(T, c*CH, basis, wi8, permS, offsS, c*CH, (c+1)*CH, ei, msg);
    }
    agg_kernel<64><<<NF, 64, 0, stream>>>(msg, permD, offsD, cntD, X2, root2, b2, (float*)d_out);

    tail_kernel<<<(NF*3 + 255)/256, 256, 0, stream>>>(pos_skip, batch_skip, (float*)d_out);
}

// Round 3
// 781.333 us; speedup vs baseline: 2.8764x; 2.8764x over previous
//
#include <hip/hip_runtime.h>
#include <hip/hip_bf16.h>

#define NC 8192
#define NF 16384
#define NE 262144
#define TROW 8000   // 125 * 64

typedef __attribute__((ext_vector_type(8))) short short8v;  // 8 bf16
typedef __attribute__((ext_vector_type(4))) float f32x4;

// ---------------- KNN (k=3), 16 lanes per query ----------------
__global__ __launch_bounds__(256) void knn_kernel(
    const float* __restrict__ pos, const int* __restrict__ batch,
    const float* __restrict__ pos_skip, const int* __restrict__ batch_skip,
    int* __restrict__ idx3, float* __restrict__ w3)
{
    const int tid = threadIdx.x;
    const int s = tid & 15;           // split lane
    const int y = blockIdx.x * 16 + (tid >> 4);
    const float py0 = pos_skip[y*3+0], py1 = pos_skip[y*3+1], py2 = pos_skip[y*3+2];
    const int by = batch_skip[y];
    float b0 = INFINITY, b1 = INFINITY, b2 = INFINITY;
    int i0 = 0, i1 = 0, i2 = 0;
    auto ins = [&](float d, int gj) {
        if (d < b2) {
            if (d < b1) {
                b2 = b1; i2 = i1;
                if (d < b0) { b1 = b0; i1 = i0; b0 = d; i0 = gj; }
                else        { b1 = d;  i1 = gj; }
            } else { b2 = d; i2 = gj; }
        }
    };
    __shared__ float sx[1024*3];
    __shared__ int   sb[1024];
    for (int tile = 0; tile < NC; tile += 1024) {
        __syncthreads();
        for (int i = tid; i < 1024*3; i += 256) sx[i] = pos[tile*3 + i];
        for (int i = tid; i < 1024;   i += 256) sb[i] = batch[tile + i];
        __syncthreads();
        for (int t = 0; t < 64; ++t) {
            const int j = t*16 + s;    // bank stride 3 across s -> conflict-free
            float dx = py0 - sx[j*3+0];
            float dy = py1 - sx[j*3+1];
            float dz = py2 - sx[j*3+2];
            float d = dx*dx + dy*dy + dz*dz;
            if (sb[j] != by) d = INFINITY;
            ins(d, tile + j);
        }
    }
    // butterfly merge across the 16 split lanes
    #pragma unroll
    for (int mask = 1; mask <= 8; mask <<= 1) {
        float c0 = __shfl_xor(b0, mask), c1 = __shfl_xor(b1, mask), c2 = __shfl_xor(b2, mask);
        int   j0 = __shfl_xor(i0, mask), j1 = __shfl_xor(i1, mask), j2 = __shfl_xor(i2, mask);
        ins(c0, j0); ins(c1, j1); ins(c2, j2);
    }
    if (s == 0) {
        idx3[y*3+0] = i0; idx3[y*3+1] = i1; idx3[y*3+2] = i2;
        w3[y*3+0] = 1.0f / fmaxf(b0, 1e-16f);
        w3[y*3+1] = 1.0f / fmaxf(b1, 1e-16f);
        w3[y*3+2] = 1.0f / fmaxf(b2, 1e-16f);
    }
}

// ---------------- interpolate + concat -> X0 [NF,128] fp32 + bf16 copy ----------------
__global__ __launch_bounds__(64) void interp_kernel(
    const float* __restrict__ x, const float* __restrict__ x_skip,
    const int* __restrict__ idx3, const float* __restrict__ w3,
    float* __restrict__ X0, __hip_bfloat16* __restrict__ Xb0)
{
    const int n = blockIdx.x, c = threadIdx.x;
    const int j0 = idx3[n*3+0], j1 = idx3[n*3+1], j2 = idx3[n*3+2];
    const float w0 = w3[n*3+0], w1 = w3[n*3+1], w2 = w3[n*3+2];
    const float inv = 1.0f / (w0 + w1 + w2);
    float h = (w0 * x[j0*64+c] + w1 * x[j1*64+c] + w2 * x[j2*64+c]) * inv;
    float xs = x_skip[n*64+c];
    X0[(size_t)n*128 + c]      = h;
    X0[(size_t)n*128 + 64 + c] = xs;
    Xb0[(size_t)n*128 + c]      = __float2bfloat16(h);
    Xb0[(size_t)n*128 + 64 + c] = __float2bfloat16(xs);
}

// ---------------- spline basis per edge + src/dst histograms ----------------
__global__ __launch_bounds__(256) void basis_kernel(
    const int* __restrict__ ei, const float* __restrict__ pos_skip,
    float* __restrict__ basis, uint2* __restrict__ wi8,
    int* __restrict__ cntD, int* __restrict__ cntS)
{
    const int e = blockIdx.x * 256 + threadIdx.x;
    const int src = ei[e], dst = ei[NE + e];
    float fr[3]; int lo[3];
    #pragma unroll
    for (int d = 0; d < 3; ++d) {
        float p = (pos_skip[dst*3+d] - pos_skip[src*3+d]) * 4.0f + 0.5f;
        p = fminf(fmaxf(p, 0.0f), 1.0f);
        float v = p * 4.0f;
        float l = fminf(floorf(v), 3.0f);
        fr[d] = v - l;
        lo[d] = (int)l;
    }
    unsigned int wlo = 0, whi = 0;
    #pragma unroll
    for (int s = 0; s < 8; ++s) {
        const int bit0 = s & 1, bit1 = (s >> 1) & 1, bit2 = (s >> 2) & 1;
        float b = (bit0 ? fr[0] : 1.0f - fr[0])
                * (bit1 ? fr[1] : 1.0f - fr[1])
                * (bit2 ? fr[2] : 1.0f - fr[2]);
        int w = (lo[0] + bit0) + 5 * (lo[1] + bit1) + 25 * (lo[2] + bit2);
        basis[(size_t)e*8 + s] = b;
        if (s < 4) wlo |= ((unsigned)w) << (8*s);
        else       whi |= ((unsigned)w) << (8*(s-4));
    }
    wi8[e] = make_uint2(wlo, whi);
    atomicAdd(&cntD[dst], 1);
    atomicAdd(&cntS[src], 1);
}

// ---------------- single-block exclusive scan over NF counts (+sentinel) ----------------
__global__ __launch_bounds__(1024) void scan_kernel(
    const int* __restrict__ cnt, int* __restrict__ offs, int* __restrict__ cursor)
{
    __shared__ int s[1024];
    __shared__ int carry_s;
    const int tid = threadIdx.x;
    if (tid == 0) carry_s = 0;
    __syncthreads();
    for (int ch = 0; ch < NF/1024; ++ch) {
        const int i = ch*1024 + tid;
        const int v = cnt[i];
        s[tid] = v;
        __syncthreads();
        for (int off = 1; off < 1024; off <<= 1) {
            int t = (tid >= off) ? s[tid - off] : 0;
            __syncthreads();
            s[tid] += t;
            __syncthreads();
        }
        const int incl  = s[tid];
        const int total = s[1023];
        const int base  = carry_s;
        const int excl  = base + incl - v;
        offs[i] = excl; cursor[i] = excl;
        __syncthreads();
        if (tid == 0) carry_s = base + total;
        __syncthreads();
    }
    if (tid == 0) offs[NF] = carry_s;
}

// ---------------- scatter: edge permutation sorted by key ----------------
__global__ __launch_bounds__(256) void scatter_kernel(
    const int* __restrict__ key, int* __restrict__ cursor, int* __restrict__ perm)
{
    const int e = blockIdx.x * 256 + threadIdx.x;
    const int k = key[e];
    const int p = atomicAdd(&cursor[k], 1);
    perm[p] = e;
}

// ---------------- W prep: [125][KIN][64] fp32 -> Wt [125][64][KIN] bf16 ----------------
template<int KIN>
__global__ __launch_bounds__(256) void wprep_kernel(
    const float* __restrict__ W, __hip_bfloat16* __restrict__ Wt)
{
    __shared__ float s[KIN*64];
    const int kern = blockIdx.x;
    const float* Wk = W + (size_t)kern * KIN * 64;
    for (int i = threadIdx.x; i < KIN*64; i += 256) s[i] = Wk[i];
    __syncthreads();
    for (int i = threadIdx.x; i < 64*(KIN/8); i += 256) {
        const int o = i / (KIN/8), kb = (i % (KIN/8)) * 8;
        union { short8v v; __hip_bfloat16 h[8]; } u;
        #pragma unroll
        for (int j = 0; j < 8; ++j) u.h[j] = __float2bfloat16(s[(kb+j)*64 + o]);
        *(short8v*)&Wt[((size_t)kern*64 + o)*KIN + kb] = u.v;
    }
}

// ---------------- T_chunk = Xb_chunk @ W  (bf16 MFMA, one-shot K) ----------------
// block: 128 rows x 64 cols (one kern); 4 waves, each 32 rows.
template<int KIN>
__global__ __launch_bounds__(256) void gemm_mfma_kernel(
    const __hip_bfloat16* __restrict__ Xb,   // [CH][KIN], chunk base pre-offset
    const __hip_bfloat16* __restrict__ Wt,   // [125][64][KIN]
    __hip_bfloat16* __restrict__ T)          // [CH][8000]
{
    constexpr int BKP = KIN + 8;             // padded row, bf16 elems (272/144 B)
    __shared__ __hip_bfloat16 As[128*BKP];
    __shared__ __hip_bfloat16 Bs[64*BKP];
    const int kern = blockIdx.x;
    const int m0   = blockIdx.y * 128;

    // stage A (128 x KIN) via 16B vectors
    for (int i = threadIdx.x; i < 128*(KIN/8); i += 256) {
        const int r = i / (KIN/8), c8 = (i % (KIN/8)) * 8;
        short8v v = *(const short8v*)&Xb[(size_t)(m0 + r)*KIN + c8];
        *(short8v*)&As[r*BKP + c8] = v;
    }
    // stage B (64 x KIN)
    const __hip_bfloat16* Wk = Wt + (size_t)kern * 64 * KIN;
    for (int i = threadIdx.x; i < 64*(KIN/8); i += 256) {
        const int r = i / (KIN/8), c8 = (i % (KIN/8)) * 8;
        short8v v = *(const short8v*)&Wk[(size_t)r*KIN + c8];
        *(short8v*)&Bs[r*BKP + c8] = v;
    }
    __syncthreads();

    const int wid  = threadIdx.x >> 6;
    const int lane = threadIdx.x & 63;
    const int lr   = lane & 15;
    const int lk   = (lane >> 4) * 8;

    f32x4 acc[2][4] = {};
    #pragma unroll
    for (int ks = 0; ks < KIN/32; ++ks) {
        short8v a0 = *(const short8v*)&As[(wid*32 +      lr)*BKP + ks*32 + lk];
        short8v a1 = *(const short8v*)&As[(wid*32 + 16 + lr)*BKP + ks*32 + lk];
        #pragma unroll
        for (int n = 0; n < 4; ++n) {
            short8v b = *(const short8v*)&Bs[(n*16 + lr)*BKP + ks*32 + lk];
            acc[0][n] = __builtin_amdgcn_mfma_f32_16x16x32_bf16(a0, b, acc[0][n], 0, 0, 0);
            acc[1][n] = __builtin_amdgcn_mfma_f32_16x16x32_bf16(a1, b, acc[1][n], 0, 0, 0);
        }
    }

    const int colBase = kern*64;
    #pragma unroll
    for (int m = 0; m < 2; ++m) {
        const int row = m0 + wid*32 + m*16 + (lane >> 4)*4;
        #pragma unroll
        for (int n = 0; n < 4; ++n) {
            const int col = colBase + n*16 + lr;
            #pragma unroll
            for (int i = 0; i < 4; ++i)
                T[(size_t)(row + i)*TROW + col] = __float2bfloat16(acc[m][n][i]);
        }
    }
}

// ---------------- per-edge message for edges with src in chunk ----------------
__global__ __launch_bounds__(256) void msg_kernel(
    const __hip_bfloat16* __restrict__ Tc, int n0,
    const float* __restrict__ basis, const uint2* __restrict__ wi8,
    const int* __restrict__ permS, const int* __restrict__ offsS,
    int c0, int c1, const int* __restrict__ esrc,
    __hip_bfloat16* __restrict__ msg)
{
    const int eBeg = offsS[c0];
    const int eEnd = offsS[c1];
    const int lane = threadIdx.x & 63;
    const int sub  = threadIdx.x >> 6;
    for (int p = eBeg + blockIdx.x*4 + sub; p < eEnd; p += gridDim.x*4) {
        const int e = permS[p];
        const int src = esrc[e];
        const uint2 w8 = wi8[e];
        const float* bs = basis + (size_t)e*8;
        const __hip_bfloat16* Trow = Tc + (size_t)(src - n0) * TROW;
        float acc = 0.0f;
        #pragma unroll
        for (int s = 0; s < 4; ++s) {
            const int wk = (w8.x >> (8*s)) & 255;
            acc += bs[s] * __bfloat162float(Trow[wk*64 + lane]);
        }
        #pragma unroll
        for (int s = 0; s < 4; ++s) {
            const int wk = (w8.y >> (8*s)) & 255;
            acc += bs[4+s] * __bfloat162float(Trow[wk*64 + lane]);
        }
        msg[(size_t)e*64 + lane] = __float2bfloat16(acc);
    }
}

// ---------------- per-dst segment mean + root + bias + ELU ----------------
template<int KIN>
__global__ __launch_bounds__(64) void agg_kernel(
    const __hip_bfloat16* __restrict__ msg, const int* __restrict__ permD,
    const int* __restrict__ offsD, const int* __restrict__ cntD,
    const float* __restrict__ X, const float* __restrict__ root,
    const float* __restrict__ bias, float* __restrict__ Xout,
    __hip_bfloat16* __restrict__ Xbout)
{
    const int n = blockIdx.x, c = threadIdx.x;
    float acc = 0.0f;
    const int beg = offsD[n], num = cntD[n];
    for (int t = 0; t < num; ++t) {
        const int e = permD[beg + t];
        acc += __bfloat162float(msg[(size_t)e*64 + c]);
    }
    const float agg = acc / fmaxf((float)num, 1.0f);
    const float* xr = X + (size_t)n * KIN;
    float r = 0.0f;
    #pragma unroll 16
    for (int i = 0; i < KIN; ++i) r = fmaf(xr[i], root[i*64 + c], r);
    float o = agg + r + bias[c];
    o = (o > 0.0f) ? o : expm1f(o);
    Xout[(size_t)n*64 + c] = o;
    if (Xbout) Xbout[(size_t)n*64 + c] = __float2bfloat16(o);
}

// ---------------- tail: pos_skip + batch_skip passthrough ----------------
__global__ __launch_bounds__(256) void tail_kernel(
    const float* __restrict__ pos_skip, const int* __restrict__ batch_skip,
    float* __restrict__ out)
{
    const int i = blockIdx.x * 256 + threadIdx.x;
    if (i < NF*3) out[1048576 + i] = pos_skip[i];
    if (i < NF)   ((int*)out)[1048576 + NF*3 + i] = batch_skip[i];
}

extern "C" void kernel_launch(void* const* d_in, const int* in_sizes, int n_in,
                              void* d_out, int out_size, void* d_ws, size_t ws_size,
                              hipStream_t stream)
{
    const float* x          = (const float*)d_in[0];
    const float* pos        = (const float*)d_in[1];
    const int*   batch      = (const int*)d_in[2];
    const float* x_skip     = (const float*)d_in[3];
    const float* pos_skip   = (const float*)d_in[4];
    const int*   batch_skip = (const int*)d_in[5];
    const int*   ei         = (const int*)d_in[6];
    const float* W0    = (const float*)d_in[7];
    const float* root0 = (const float*)d_in[8];
    const float* b0    = (const float*)d_in[9];
    const float* W1    = (const float*)d_in[10];
    const float* root1 = (const float*)d_in[11];
    const float* b1    = (const float*)d_in[12];
    const float* W2    = (const float*)d_in[13];
    const float* root2 = (const float*)d_in[14];
    const float* b2    = (const float*)d_in[15];

    char* wp = (char*)d_ws;
    size_t used = 0;
    auto carve = [&](size_t bytes) {
        char* p = wp;
        size_t a = (bytes + 255) & ~(size_t)255;
        wp += a; used += a;
        return p;
    };
    float* X0    = (float*)carve((size_t)NF * 128 * 4);
    float* X1    = (float*)carve((size_t)NF * 64 * 4);
    float* X2    = (float*)carve((size_t)NF * 64 * 4);
    __hip_bfloat16* Xb0 = (__hip_bfloat16*)carve((size_t)NF * 128 * 2);
    __hip_bfloat16* Xb1 = (__hip_bfloat16*)carve((size_t)NF * 64 * 2);
    __hip_bfloat16* Xb2 = (__hip_bfloat16*)carve((size_t)NF * 64 * 2);
    __hip_bfloat16* Wt0 = (__hip_bfloat16*)carve((size_t)125 * 128 * 64 * 2);
    __hip_bfloat16* Wt1 = (__hip_bfloat16*)carve((size_t)125 * 64 * 64 * 2);
    __hip_bfloat16* Wt2 = (__hip_bfloat16*)carve((size_t)125 * 64 * 64 * 2);
    float* basis = (float*)carve((size_t)NE * 8 * 4);
    uint2* wi8   = (uint2*)carve((size_t)NE * 8);
    __hip_bfloat16* msg = (__hip_bfloat16*)carve((size_t)NE * 64 * 2);
    int*   idx3  = (int*)carve((size_t)NF * 3 * 4);
    float* w3    = (float*)carve((size_t)NF * 3 * 4);
    int*   cntD    = (int*)carve((size_t)NF * 4);
    int*   offsD   = (int*)carve((size_t)(NF+1) * 4);
    int*   cursorD = (int*)carve((size_t)NF * 4);
    int*   permD   = (int*)carve((size_t)NE * 4);
    int*   cntS    = (int*)carve((size_t)NF * 4);
    int*   offsS   = (int*)carve((size_t)(NF+1) * 4);
    int*   cursorS = (int*)carve((size_t)NF * 4);
    int*   permS   = (int*)carve((size_t)NE * 4);
    // T chunk gets whatever remains
    size_t remain = (ws_size > used) ? (ws_size - used) : 0;
    int CH = NF;
    while (CH > 512 && (size_t)CH * TROW * 2 > remain) CH >>= 1;
    __hip_bfloat16* T = (__hip_bfloat16*)wp;
    const int NCH = NF / CH;

    hipMemsetAsync(cntD, 0, (size_t)NF * 4, stream);
    hipMemsetAsync(cntS, 0, (size_t)NF * 4, stream);
    knn_kernel<<<NF/16, 256, 0, stream>>>(pos, batch, pos_skip, batch_skip, idx3, w3);
    interp_kernel<<<NF, 64, 0, stream>>>(x, x_skip, idx3, w3, X0, Xb0);
    basis_kernel<<<NE/256, 256, 0, stream>>>(ei, pos_skip, basis, wi8, cntD, cntS);
    scan_kernel<<<1, 1024, 0, stream>>>(cntD, offsD, cursorD);
    scan_kernel<<<1, 1024, 0, stream>>>(cntS, offsS, cursorS);
    scatter_kernel<<<NE/256, 256, 0, stream>>>(ei + NE, cursorD, permD);
    scatter_kernel<<<NE/256, 256, 0, stream>>>(ei,      cursorS, permS);
    wprep_kernel<128><<<125, 256, 0, stream>>>(W0, Wt0);
    wprep_kernel<64><<<125, 256, 0, stream>>>(W1, Wt1);
    wprep_kernel<64><<<125, 256, 0, stream>>>(W2, Wt2);

    // layer 0: in=128
    for (int c = 0; c < NCH; ++c) {
        gemm_mfma_kernel<128><<<dim3(125, CH/128), 256, 0, stream>>>(Xb0 + (size_t)c*CH*128, Wt0, T);
        msg_kernel<<<2048, 256, 0, stream>>>(T, c*CH, basis, wi8, permS, offsS, c*CH, (c+1)*CH, ei, msg);
    }
    agg_kernel<128><<<NF, 64, 0, stream>>>(msg, permD, offsD, cntD, X0, root0, b0, X1, Xb1);
    // layer 1: in=64
    for (int c = 0; c < NCH; ++c) {
        gemm_mfma_kernel<64><<<dim3(125, CH/128), 256, 0, stream>>>(Xb1 + (size_t)c*CH*64, Wt1, T);
        msg_kernel<<<2048, 256, 0, stream>>>(T, c*CH, basis, wi8, permS, offsS, c*CH, (c+1)*CH, ei, msg);
    }
    agg_kernel<64><<<NF, 64, 0, stream>>>(msg, permD, offsD, cntD, X1, root1, b1, X2, Xb2);
    // layer 2: in=64, h -> d_out
    for (int c = 0; c < NCH; ++c) {
        gemm_mfma_kernel<64><<<dim3(125, CH/128), 256, 0, stream>>>(Xb2 + (size_t)c*CH*64, Wt2, T);
        msg_kernel<<<2048, 256, 0, stream>>>(T, c*CH, basis, wi8, permS, offsS, c*CH, (c+1)*CH, ei, msg);
    }
    agg_kernel<64><<<NF, 64, 0, stream>>>(msg, permD, offsD, cntD, X2, root2, b2, (float*)d_out, (__hip_bfloat16*)nullptr);

    tail_kernel<<<(NF*3 + 255)/256, 256, 0, stream>>>(pos_skip, batch_skip, (float*)d_out);
}